// Round 1
// baseline (673.095 us; speedup 1.0000x reference)
//
#include <hip/hip_runtime.h>

// MultiheadAtt: B=4, S=2048, D=512, H=8, HD=64.
// Reference does q.reshape(B*H, -1, HD) as a RAW row-major reshape:
//   chunk c = 8*b + s/256, l = (s%256)*8 + (d/64), hd = d%64, L=2048.
// Flat (B,S,D) row-major == flat [32][2048][64] chunk layout (reshape is a no-op),
// so q/k/v buffers need no physical rearrangement.
// Outputs concatenated: out (4*2048*512 f32) then probs (32*2048*2048 f32).

typedef __attribute__((ext_vector_type(4))) float fvec4;
typedef __attribute__((ext_vector_type(4))) float f32x4;
typedef __attribute__((ext_vector_type(8))) short bf16x8;

__device__ inline unsigned short f2bf_rne(float x) {
    unsigned u = __builtin_bit_cast(unsigned, x);
    unsigned r = (u + 0x7FFFu + ((u >> 16) & 1u)) >> 16;
    return (unsigned short)r;
}
__device__ inline float bf2f(unsigned short h) {
    unsigned u = ((unsigned)h) << 16;
    return __builtin_bit_cast(float, u);
}

// C[M][N] = scale * sum_k A[m][k]*Bt[n][k] (+ bias[n]).  A:[M][K] lda, Bt:[N][K] ldb.
// SPLIT=true: fp32-accurate via bf16 hi/lo 3-term MFMA. Tile 64x64, BK=32, 4 waves.
template <bool SPLIT>
__global__ __launch_bounds__(256) void gemm_bt(
    const float* __restrict__ A, int lda, long long sA,
    const float* __restrict__ B, int ldb, long long sB,
    float* __restrict__ C, int ldc, long long sC,
    const float* __restrict__ bias, float scale, int K)
{
    __shared__ __align__(16) unsigned short Ah[64][40];
    __shared__ __align__(16) unsigned short Al[64][40];
    __shared__ __align__(16) unsigned short Bh[64][40];
    __shared__ __align__(16) unsigned short Bl[64][40];

    const int tid  = threadIdx.x;
    const int lane = tid & 63;
    const int wv   = tid >> 6;
    const int z    = blockIdx.z;
    A += (long long)z * sA;
    B += (long long)z * sB;
    C += (long long)z * sC;
    const int row0 = blockIdx.x * 64;
    const int col0 = blockIdx.y * 64;

    f32x4 acc[4];
#pragma unroll
    for (int i = 0; i < 4; i++)
#pragma unroll
        for (int r = 0; r < 4; r++) acc[i][r] = 0.f;

    // loader: thread t handles row t>>2 (0..63), cols (t&3)*8 .. +8
    const int lr = tid >> 2;
    const int lc = (tid & 3) * 8;

    const int ar = (wv << 4) + (lane & 15);   // A row this wave reads
    const int kk = (lane >> 4) << 3;          // k-offset within BK=32

    for (int k0 = 0; k0 < K; k0 += 32) {
        const float* ap = A + (long long)(row0 + lr) * lda + k0 + lc;
        fvec4 a0 = *(const fvec4*)ap;
        fvec4 a1 = *(const fvec4*)(ap + 4);
        const float* bp = B + (long long)(col0 + lr) * ldb + k0 + lc;
        fvec4 b0 = *(const fvec4*)bp;
        fvec4 b1 = *(const fvec4*)(bp + 4);

        __syncthreads();  // previous iteration's frag reads done before overwrite
#pragma unroll
        for (int j = 0; j < 4; j++) {
            unsigned short h;
            h = f2bf_rne(a0[j]); Ah[lr][lc + j] = h;
            if (SPLIT) Al[lr][lc + j] = f2bf_rne(a0[j] - bf2f(h));
            h = f2bf_rne(a1[j]); Ah[lr][lc + 4 + j] = h;
            if (SPLIT) Al[lr][lc + 4 + j] = f2bf_rne(a1[j] - bf2f(h));
            h = f2bf_rne(b0[j]); Bh[lr][lc + j] = h;
            if (SPLIT) Bl[lr][lc + j] = f2bf_rne(b0[j] - bf2f(h));
            h = f2bf_rne(b1[j]); Bh[lr][lc + 4 + j] = h;
            if (SPLIT) Bl[lr][lc + 4 + j] = f2bf_rne(b1[j] - bf2f(h));
        }
        __syncthreads();

        bf16x8 aH = *(const bf16x8*)&Ah[ar][kk];
        bf16x8 aL;
        if (SPLIT) aL = *(const bf16x8*)&Al[ar][kk];
#pragma unroll
        for (int cb = 0; cb < 4; cb++) {
            const int br = (cb << 4) + (lane & 15);
            bf16x8 bH = *(const bf16x8*)&Bh[br][kk];
            acc[cb] = __builtin_amdgcn_mfma_f32_16x16x32_bf16(aH, bH, acc[cb], 0, 0, 0);
            if (SPLIT) {
                bf16x8 bL = *(const bf16x8*)&Bl[br][kk];
                acc[cb] = __builtin_amdgcn_mfma_f32_16x16x32_bf16(aH, bL, acc[cb], 0, 0, 0);
                acc[cb] = __builtin_amdgcn_mfma_f32_16x16x32_bf16(aL, bH, acc[cb], 0, 0, 0);
            }
        }
    }

    // C/D layout (m89-verified): col = lane&15, row = (lane>>4)*4 + reg
#pragma unroll
    for (int cb = 0; cb < 4; cb++) {
#pragma unroll
        for (int r = 0; r < 4; r++) {
            const int row = row0 + (wv << 4) + ((lane >> 4) << 2) + r;
            const int col = col0 + (cb << 4) + (lane & 15);
            float v = acc[cb][r] * scale;
            if (bias) v += bias[col];
            C[(long long)row * ldc + col] = v;
        }
    }
}

// In-place row softmax over rows of length 2048 (one block per row).
__global__ __launch_bounds__(256) void softmax_rows(float* __restrict__ P)
{
    const long long row = blockIdx.x;
    float* p = P + row * 2048;
    const int t = threadIdx.x;

    fvec4 v0 = *(const fvec4*)(p + t * 8);
    fvec4 v1 = *(const fvec4*)(p + t * 8 + 4);

    float m = v0[0];
#pragma unroll
    for (int j = 1; j < 4; j++) m = fmaxf(m, v0[j]);
#pragma unroll
    for (int j = 0; j < 4; j++) m = fmaxf(m, v1[j]);
#pragma unroll
    for (int off = 32; off >= 1; off >>= 1) m = fmaxf(m, __shfl_xor(m, off, 64));

    __shared__ float red[8];
    if ((t & 63) == 0) red[t >> 6] = m;
    __syncthreads();
    m = fmaxf(fmaxf(red[0], red[1]), fmaxf(red[2], red[3]));

    float s = 0.f;
#pragma unroll
    for (int j = 0; j < 4; j++) { v0[j] = __expf(v0[j] - m); s += v0[j]; }
#pragma unroll
    for (int j = 0; j < 4; j++) { v1[j] = __expf(v1[j] - m); s += v1[j]; }
#pragma unroll
    for (int off = 32; off >= 1; off >>= 1) s += __shfl_xor(s, off, 64);
    if ((t & 63) == 0) red[4 + (t >> 6)] = s;
    __syncthreads();
    s = (red[4] + red[5]) + (red[6] + red[7]);

    const float inv = 1.f / s;
    v0 *= inv; v1 *= inv;
    *(fvec4*)(p + t * 8)     = v0;
    *(fvec4*)(p + t * 8 + 4) = v1;
}

// Transpose the four 512x512 weight matrices: out[z][n][k] = W_z[k][n]
__global__ __launch_bounds__(256) void transpose512(
    const float* __restrict__ W0, const float* __restrict__ W1,
    const float* __restrict__ W2, const float* __restrict__ W3,
    float* __restrict__ out)
{
    const float* W = blockIdx.z == 0 ? W0 : blockIdx.z == 1 ? W1 : blockIdx.z == 2 ? W2 : W3;
    float* o = out + (long long)blockIdx.z * 262144;
    __shared__ float t[32][33];
    const int x = threadIdx.x, y = threadIdx.y;  // block (32,8)
    const int n0 = blockIdx.x * 32, k0 = blockIdx.y * 32;
#pragma unroll
    for (int j = 0; j < 4; j++) t[y + 8 * j][x] = W[(long long)(k0 + y + 8 * j) * 512 + n0 + x];
    __syncthreads();
#pragma unroll
    for (int j = 0; j < 4; j++) o[(long long)(n0 + y + 8 * j) * 512 + k0 + x] = t[x][y + 8 * j];
}

// vt[c][hd][l] = v[m][n], c=m>>8, l=(m&255)*8+(n>>6), hd=n&63. Block: 8 rows of v.
__global__ __launch_bounds__(256) void vtrans(const float* __restrict__ V, float* __restrict__ VT)
{
    __shared__ float t[8][513];
    const int tid = threadIdx.x;
    const int m0 = blockIdx.x * 8;
    const int r = tid >> 5, c0 = (tid & 31) * 16;
    const float* src = V + (long long)(m0 + r) * 512 + c0;
#pragma unroll
    for (int j = 0; j < 4; j++) {
        fvec4 v = *(const fvec4*)(src + 4 * j);
#pragma unroll
        for (int q = 0; q < 4; q++) t[r][c0 + 4 * j + q] = v[q];
    }
    __syncthreads();
    const int c  = m0 >> 8;
    const int l0 = (m0 & 255) * 8;
    const int i  = tid & 63;
    const int hd0 = tid >> 6;
    float* dst = VT + (long long)c * 131072 + l0 + i;
#pragma unroll
    for (int j = 0; j < 16; j++) {
        const int hd = hd0 + 4 * j;
        dst[(long long)hd * 2048] = t[i >> 3][hd + 64 * (i & 7)];
    }
}

extern "C" void kernel_launch(void* const* d_in, const int* in_sizes, int n_in,
                              void* d_out, int out_size, void* d_ws, size_t ws_size,
                              hipStream_t stream)
{
    const float* query = (const float*)d_in[0];
    const float* key_  = (const float*)d_in[1];
    const float* value = (const float*)d_in[2];
    const float* Wq = (const float*)d_in[3];
    const float* bq = (const float*)d_in[4];
    const float* Wk = (const float*)d_in[5];
    const float* bk = (const float*)d_in[6];
    const float* Wv = (const float*)d_in[7];
    const float* bv = (const float*)d_in[8];
    const float* Wo = (const float*)d_in[9];
    const float* bo = (const float*)d_in[10];

    float* out   = (float*)d_out;
    float* probs = out + 4194304LL;  // 32*2048*2048

    // workspace layout (needs ~88 MB)
    float* qbuf = (float*)d_ws;
    float* kbuf = qbuf + 4194304LL;
    float* vbuf = kbuf + 4194304LL;
    float* vtb  = vbuf + 4194304LL;
    float* aob  = vtb  + 4194304LL;
    float* WT   = aob  + 4194304LL;  // 4 x 262144 (WqT, WkT, WvT, WoT)

    transpose512<<<dim3(16, 16, 4), dim3(32, 8, 1), 0, stream>>>(Wq, Wk, Wv, Wo, WT);

    // projections: x @ W + b  (BT-gemm against pre-transposed W)
    gemm_bt<true><<<dim3(128, 8, 1), 256, 0, stream>>>(query, 512, 0, WT,          512, 0, qbuf, 512, 0, bq, 1.f, 512);
    gemm_bt<true><<<dim3(128, 8, 1), 256, 0, stream>>>(key_,  512, 0, WT + 262144, 512, 0, kbuf, 512, 0, bk, 1.f, 512);
    gemm_bt<true><<<dim3(128, 8, 1), 256, 0, stream>>>(value, 512, 0, WT + 524288, 512, 0, vbuf, 512, 0, bv, 1.f, 512);

    vtrans<<<dim3(1024, 1, 1), 256, 0, stream>>>(vbuf, vtb);

    // scores = q @ k^T / 8 per chunk -> written raw into probs region
    gemm_bt<true><<<dim3(32, 32, 32), 256, 0, stream>>>(qbuf, 64, 131072, kbuf, 64, 131072,
                                                        probs, 2048, 4194304LL, nullptr, 0.125f, 64);
    // softmax in place
    softmax_rows<<<dim3(65536, 1, 1), 256, 0, stream>>>(probs);

    // ao = probs @ v  (Bt = vt)
    gemm_bt<false><<<dim3(32, 1, 32), 256, 0, stream>>>(probs, 2048, 4194304LL, vtb, 2048, 131072,
                                                        aob, 64, 131072, nullptr, 1.f, 2048);
    // out = ao @ Wo + bo
    gemm_bt<true><<<dim3(128, 8, 1), 256, 0, stream>>>(aob, 512, 0, WT + 786432, 512, 0,
                                                       out, 512, 0, bo, 1.f, 512);
}

// Round 2
// 357.691 us; speedup vs baseline: 1.8818x; 1.8818x over previous
//
#include <hip/hip_runtime.h>

// MultiheadAtt: B=4, S=2048, D=512, H=8, HD=64.
// .view() reshape is a raw row-major no-op: chunk c = m>>8 (m = token),
// l = (m&255)*8 + (n>>6), hd = n&63, and flat [m][n] == [c][l][hd] with
// index c*131072 + l*64 + hd.  Outputs: out (4*2048*512 f32) then probs
// (32*2048*2048 f32).
//
// Pipeline: WT transpose -> qkv projection (split bf16 hi/lo out) ->
// v transpose (vt[c][hd][l]) -> fused scores+softmax+PV (probs written once,
// normalized; scores recomputed for the normalized write; no max-subtract:
// |s| <= |q||k|/8 <= 8 so exp never overflows fp32) -> out projection.

typedef __attribute__((ext_vector_type(4))) float fvec4;
typedef __attribute__((ext_vector_type(4))) float f32x4;
typedef __attribute__((ext_vector_type(8))) short bf16x8;
typedef __attribute__((ext_vector_type(4))) short bf16x4;

__device__ inline unsigned short f2bf_rne(float x) {
    unsigned u = __builtin_bit_cast(unsigned, x);
    unsigned r = (u + 0x7FFFu + ((u >> 16) & 1u)) >> 16;
    return (unsigned short)r;
}
__device__ inline float bf2f(unsigned short h) {
    unsigned u = ((unsigned)h) << 16;
    return __builtin_bit_cast(float, u);
}

// ---------------------------------------------------------------- out-proj
// C[M][N] = scale * sum_k A[m][k]*Bt[n][k] (+ bias[n]).  fp32-accurate split.
template <bool SPLIT>
__global__ __launch_bounds__(256) void gemm_bt(
    const float* __restrict__ A, int lda, long long sA,
    const float* __restrict__ B, int ldb, long long sB,
    float* __restrict__ C, int ldc, long long sC,
    const float* __restrict__ bias, float scale, int K)
{
    __shared__ __align__(16) unsigned short Ah[64][40];
    __shared__ __align__(16) unsigned short Al[64][40];
    __shared__ __align__(16) unsigned short Bh[64][40];
    __shared__ __align__(16) unsigned short Bl[64][40];

    const int tid  = threadIdx.x;
    const int lane = tid & 63;
    const int wv   = tid >> 6;
    const int z    = blockIdx.z;
    A += (long long)z * sA;
    B += (long long)z * sB;
    C += (long long)z * sC;
    const int row0 = blockIdx.x * 64;
    const int col0 = blockIdx.y * 64;

    f32x4 acc[4];
#pragma unroll
    for (int i = 0; i < 4; i++)
#pragma unroll
        for (int r = 0; r < 4; r++) acc[i][r] = 0.f;

    const int lr = tid >> 2;
    const int lc = (tid & 3) * 8;
    const int ar = (wv << 4) + (lane & 15);
    const int kk = (lane >> 4) << 3;

    for (int k0 = 0; k0 < K; k0 += 32) {
        const float* ap = A + (long long)(row0 + lr) * lda + k0 + lc;
        fvec4 a0 = *(const fvec4*)ap;
        fvec4 a1 = *(const fvec4*)(ap + 4);
        const float* bp = B + (long long)(col0 + lr) * ldb + k0 + lc;
        fvec4 b0 = *(const fvec4*)bp;
        fvec4 b1 = *(const fvec4*)(bp + 4);

        __syncthreads();
#pragma unroll
        for (int j = 0; j < 4; j++) {
            unsigned short h;
            h = f2bf_rne(a0[j]); Ah[lr][lc + j] = h;
            if (SPLIT) Al[lr][lc + j] = f2bf_rne(a0[j] - bf2f(h));
            h = f2bf_rne(a1[j]); Ah[lr][lc + 4 + j] = h;
            if (SPLIT) Al[lr][lc + 4 + j] = f2bf_rne(a1[j] - bf2f(h));
            h = f2bf_rne(b0[j]); Bh[lr][lc + j] = h;
            if (SPLIT) Bl[lr][lc + j] = f2bf_rne(b0[j] - bf2f(h));
            h = f2bf_rne(b1[j]); Bh[lr][lc + 4 + j] = h;
            if (SPLIT) Bl[lr][lc + 4 + j] = f2bf_rne(b1[j] - bf2f(h));
        }
        __syncthreads();

        bf16x8 aH = *(const bf16x8*)&Ah[ar][kk];
        bf16x8 aL;
        if (SPLIT) aL = *(const bf16x8*)&Al[ar][kk];
#pragma unroll
        for (int cb = 0; cb < 4; cb++) {
            const int br = (cb << 4) + (lane & 15);
            bf16x8 bH = *(const bf16x8*)&Bh[br][kk];
            acc[cb] = __builtin_amdgcn_mfma_f32_16x16x32_bf16(aH, bH, acc[cb], 0, 0, 0);
            if (SPLIT) {
                bf16x8 bL = *(const bf16x8*)&Bl[br][kk];
                acc[cb] = __builtin_amdgcn_mfma_f32_16x16x32_bf16(aH, bL, acc[cb], 0, 0, 0);
                acc[cb] = __builtin_amdgcn_mfma_f32_16x16x32_bf16(aL, bH, acc[cb], 0, 0, 0);
            }
        }
    }

#pragma unroll
    for (int cb = 0; cb < 4; cb++) {
#pragma unroll
        for (int r = 0; r < 4; r++) {
            const int row = row0 + (wv << 4) + ((lane >> 4) << 2) + r;
            const int col = col0 + (cb << 4) + (lane & 15);
            float v = acc[cb][r] * scale;
            if (bias) v += bias[col];
            C[(long long)row * ldc + col] = v;
        }
    }
}

// ------------------------------------------------- qkv projection, bf16 out
// One launch, z = 0(q) / 1(k) / 2(v). Writes hi (and lo for q,k) bf16 buffers.
__global__ __launch_bounds__(256) void proj_qkv(
    const float* __restrict__ X0, const float* __restrict__ X1, const float* __restrict__ X2,
    const float* __restrict__ WT,
    const float* __restrict__ b0_, const float* __restrict__ b1_, const float* __restrict__ b2_,
    unsigned short* __restrict__ qh, unsigned short* __restrict__ ql,
    unsigned short* __restrict__ kh, unsigned short* __restrict__ kl,
    unsigned short* __restrict__ vh)
{
    __shared__ __align__(16) unsigned short Ah[64][40];
    __shared__ __align__(16) unsigned short Al[64][40];
    __shared__ __align__(16) unsigned short Bh[64][40];
    __shared__ __align__(16) unsigned short Bl[64][40];

    const int tid  = threadIdx.x;
    const int lane = tid & 63;
    const int wv   = tid >> 6;
    const int z    = blockIdx.z;
    const float* A    = z == 0 ? X0 : z == 1 ? X1 : X2;
    const float* B    = WT + (long long)z * 262144;
    const float* bias = z == 0 ? b0_ : z == 1 ? b1_ : b2_;
    unsigned short* Oh = z == 0 ? qh : z == 1 ? kh : vh;
    unsigned short* Ol = z == 0 ? ql : z == 1 ? kl : nullptr;

    const int row0 = blockIdx.x * 64;
    const int col0 = blockIdx.y * 64;

    f32x4 acc[4];
#pragma unroll
    for (int i = 0; i < 4; i++)
#pragma unroll
        for (int r = 0; r < 4; r++) acc[i][r] = 0.f;

    const int lr = tid >> 2;
    const int lc = (tid & 3) * 8;
    const int ar = (wv << 4) + (lane & 15);
    const int kk = (lane >> 4) << 3;

    for (int k0 = 0; k0 < 512; k0 += 32) {
        const float* ap = A + (long long)(row0 + lr) * 512 + k0 + lc;
        fvec4 a0 = *(const fvec4*)ap;
        fvec4 a1 = *(const fvec4*)(ap + 4);
        const float* bp = B + (long long)(col0 + lr) * 512 + k0 + lc;
        fvec4 b0 = *(const fvec4*)bp;
        fvec4 b1 = *(const fvec4*)(bp + 4);

        __syncthreads();
#pragma unroll
        for (int j = 0; j < 4; j++) {
            unsigned short h;
            h = f2bf_rne(a0[j]); Ah[lr][lc + j] = h;     Al[lr][lc + j] = f2bf_rne(a0[j] - bf2f(h));
            h = f2bf_rne(a1[j]); Ah[lr][lc + 4 + j] = h; Al[lr][lc + 4 + j] = f2bf_rne(a1[j] - bf2f(h));
            h = f2bf_rne(b0[j]); Bh[lr][lc + j] = h;     Bl[lr][lc + j] = f2bf_rne(b0[j] - bf2f(h));
            h = f2bf_rne(b1[j]); Bh[lr][lc + 4 + j] = h; Bl[lr][lc + 4 + j] = f2bf_rne(b1[j] - bf2f(h));
        }
        __syncthreads();

        bf16x8 aH = *(const bf16x8*)&Ah[ar][kk];
        bf16x8 aL = *(const bf16x8*)&Al[ar][kk];
#pragma unroll
        for (int cb = 0; cb < 4; cb++) {
            const int br = (cb << 4) + (lane & 15);
            bf16x8 bH = *(const bf16x8*)&Bh[br][kk];
            bf16x8 bL = *(const bf16x8*)&Bl[br][kk];
            acc[cb] = __builtin_amdgcn_mfma_f32_16x16x32_bf16(aH, bH, acc[cb], 0, 0, 0);
            acc[cb] = __builtin_amdgcn_mfma_f32_16x16x32_bf16(aH, bL, acc[cb], 0, 0, 0);
            acc[cb] = __builtin_amdgcn_mfma_f32_16x16x32_bf16(aL, bH, acc[cb], 0, 0, 0);
        }
    }

#pragma unroll
    for (int cb = 0; cb < 4; cb++) {
#pragma unroll
        for (int r = 0; r < 4; r++) {
            const int row = row0 + (wv << 4) + ((lane >> 4) << 2) + r;
            const int col = col0 + (cb << 4) + (lane & 15);
            float v = acc[cb][r] + bias[col];
            unsigned short h = f2bf_rne(v);
            Oh[(long long)row * 512 + col] = h;
            if (Ol) Ol[(long long)row * 512 + col] = f2bf_rne(v - bf2f(h));
        }
    }
}

// ---------------------------------------------------------- weight transpose
__global__ __launch_bounds__(256) void transpose512(
    const float* __restrict__ W0, const float* __restrict__ W1,
    const float* __restrict__ W2, const float* __restrict__ W3,
    float* __restrict__ out)
{
    const float* W = blockIdx.z == 0 ? W0 : blockIdx.z == 1 ? W1 : blockIdx.z == 2 ? W2 : W3;
    float* o = out + (long long)blockIdx.z * 262144;
    __shared__ float t[32][33];
    const int x = threadIdx.x, y = threadIdx.y;
    const int n0 = blockIdx.x * 32, k0 = blockIdx.y * 32;
#pragma unroll
    for (int j = 0; j < 4; j++) t[y + 8 * j][x] = W[(long long)(k0 + y + 8 * j) * 512 + n0 + x];
    __syncthreads();
#pragma unroll
    for (int j = 0; j < 4; j++) o[(long long)(n0 + y + 8 * j) * 512 + k0 + x] = t[x][y + 8 * j];
}

// ----------------------------------------------- v transpose: vt[c][hd][l]
// vh flat is [c][l][hd] (no-op reshape); emit bf16 vt with l contiguous.
__global__ __launch_bounds__(256) void vtrans2(
    const unsigned short* __restrict__ vh, unsigned short* __restrict__ vt)
{
    __shared__ __align__(16) unsigned short t[64][80];
    const int tid = threadIdx.x;
    const int c = blockIdx.y;
    const int l0 = blockIdx.x * 64;
    const long long cb = (long long)c * 131072;
    const int rrow = tid >> 3, ccol = (tid & 7) * 8;
#pragma unroll
    for (int rr = 0; rr < 2; rr++)
        *(bf16x8*)&t[rrow + rr * 32][ccol] =
            *(const bf16x8*)(vh + cb + (long long)(l0 + rrow + rr * 32) * 64 + ccol);
    __syncthreads();
#pragma unroll
    for (int rr = 0; rr < 2; rr++) {
        const int hd = rrow + rr * 32;
        bf16x8 o;
#pragma unroll
        for (int q2 = 0; q2 < 8; q2++) o[q2] = (short)t[ccol + q2][hd];
        *(bf16x8*)(vt + cb + (long long)hd * 2048 + l0 + ccol) = o;
    }
}

// --------------------------------------- fused scores + softmax + PV + probs
// Block = (row-block of 64 q-rows) x (chunk). 4 waves; wave owns 16 rows.
__global__ __launch_bounds__(256) void fused_attn(
    const unsigned short* __restrict__ qh, const unsigned short* __restrict__ ql,
    const unsigned short* __restrict__ kh, const unsigned short* __restrict__ kl,
    const unsigned short* __restrict__ vt,
    float* __restrict__ probs, float* __restrict__ ao)
{
    __shared__ __align__(16) unsigned short skh[64][80];
    __shared__ __align__(16) unsigned short skl[64][80];
    __shared__ __align__(16) unsigned short svt[64][80];
    __shared__ __align__(16) unsigned short sP[4][16][68];  // per-wave P strip

    const int tid  = threadIdx.x;
    const int lane = tid & 63;
    const int wv   = tid >> 6;
    const int c    = blockIdx.y;
    const int row0 = blockIdx.x * 64;
    const long long cbase = (long long)c * 131072;

    const int l15 = lane & 15;
    const int kk  = (lane >> 4) << 3;

    // Q fragments (held for whole kernel)
    const int arow = row0 + wv * 16 + l15;
    bf16x8 aH[2], aL[2];
    {
        const unsigned short* qp  = qh + cbase + (long long)arow * 64;
        const unsigned short* qlp = ql + cbase + (long long)arow * 64;
        aH[0] = *(const bf16x8*)(qp + kk);
        aH[1] = *(const bf16x8*)(qp + 32 + kk);
        aL[0] = *(const bf16x8*)(qlp + kk);
        aL[1] = *(const bf16x8*)(qlp + 32 + kk);
    }

    const int srow = tid >> 3;
    const int scol = (tid & 7) * 8;

    f32x4 acc_o[4];
#pragma unroll
    for (int i = 0; i < 4; i++)
#pragma unroll
        for (int r = 0; r < 4; r++) acc_o[i][r] = 0.f;
    float rsum[4] = {0.f, 0.f, 0.f, 0.f};

    // ---- pass 1: S, exp, row-sums, PV (unnormalized)
    for (int j = 0; j < 32; j++) {
        __syncthreads();
        const long long ktb = cbase + (long long)j * 4096;
        const long long vtb = cbase + j * 64;
#pragma unroll
        for (int rr = 0; rr < 2; rr++) {
            const int r2 = srow + rr * 32;
            *(bf16x8*)&skh[r2][scol] = *(const bf16x8*)(kh + ktb + (long long)r2 * 64 + scol);
            *(bf16x8*)&skl[r2][scol] = *(const bf16x8*)(kl + ktb + (long long)r2 * 64 + scol);
            *(bf16x8*)&svt[r2][scol] = *(const bf16x8*)(vt + vtb + (long long)r2 * 2048 + scol);
        }
        __syncthreads();

        f32x4 s[4];
#pragma unroll
        for (int cb = 0; cb < 4; cb++)
#pragma unroll
            for (int r = 0; r < 4; r++) s[cb][r] = 0.f;
#pragma unroll
        for (int ks = 0; ks < 2; ks++) {
#pragma unroll
            for (int cb = 0; cb < 4; cb++) {
                const int col = cb * 16 + l15;
                bf16x8 bH = *(const bf16x8*)&skh[col][ks * 32 + kk];
                bf16x8 bL = *(const bf16x8*)&skl[col][ks * 32 + kk];
                s[cb] = __builtin_amdgcn_mfma_f32_16x16x32_bf16(aH[ks], bH, s[cb], 0, 0, 0);
                s[cb] = __builtin_amdgcn_mfma_f32_16x16x32_bf16(aH[ks], bL, s[cb], 0, 0, 0);
                s[cb] = __builtin_amdgcn_mfma_f32_16x16x32_bf16(aL[ks], bH, s[cb], 0, 0, 0);
            }
        }
#pragma unroll
        for (int cb = 0; cb < 4; cb++) {
#pragma unroll
            for (int r = 0; r < 4; r++) {
                float p = __expf(s[cb][r] * 0.125f);
                rsum[r] += p;
                sP[wv][(lane >> 4) * 4 + r][cb * 16 + l15] = f2bf_rne(p);
            }
        }
        // PV: A-frag from own wave's sP strip (no barrier needed)
#pragma unroll
        for (int ks = 0; ks < 2; ks++) {
            bf16x4 p0 = *(const bf16x4*)&sP[wv][l15][ks * 32 + kk];
            bf16x4 p1 = *(const bf16x4*)&sP[wv][l15][ks * 32 + kk + 4];
            bf16x8 pa;
#pragma unroll
            for (int q2 = 0; q2 < 4; q2++) { pa[q2] = p0[q2]; pa[4 + q2] = p1[q2]; }
#pragma unroll
            for (int co = 0; co < 4; co++) {
                bf16x8 bV = *(const bf16x8*)&svt[co * 16 + l15][ks * 32 + kk];
                acc_o[co] = __builtin_amdgcn_mfma_f32_16x16x32_bf16(pa, bV, acc_o[co], 0, 0, 0);
            }
        }
    }

    // row sums -> 1/sum (reduce across the 16 col-lanes)
#pragma unroll
    for (int r = 0; r < 4; r++) {
        float s = rsum[r];
        s += __shfl_xor(s, 1, 64);
        s += __shfl_xor(s, 2, 64);
        s += __shfl_xor(s, 4, 64);
        s += __shfl_xor(s, 8, 64);
        rsum[r] = 1.f / s;
    }

    // O epilogue
#pragma unroll
    for (int co = 0; co < 4; co++) {
#pragma unroll
        for (int r = 0; r < 4; r++) {
            const int orow = row0 + wv * 16 + (lane >> 4) * 4 + r;
            ao[cbase + (long long)orow * 64 + co * 16 + l15] = acc_o[co][r] * rsum[r];
        }
    }

    // ---- pass 2: recompute S, write normalized probs
    for (int j = 0; j < 32; j++) {
        __syncthreads();
        const long long ktb = cbase + (long long)j * 4096;
#pragma unroll
        for (int rr = 0; rr < 2; rr++) {
            const int r2 = srow + rr * 32;
            *(bf16x8*)&skh[r2][scol] = *(const bf16x8*)(kh + ktb + (long long)r2 * 64 + scol);
            *(bf16x8*)&skl[r2][scol] = *(const bf16x8*)(kl + ktb + (long long)r2 * 64 + scol);
        }
        __syncthreads();

        f32x4 s[4];
#pragma unroll
        for (int cb = 0; cb < 4; cb++)
#pragma unroll
            for (int r = 0; r < 4; r++) s[cb][r] = 0.f;
#pragma unroll
        for (int ks = 0; ks < 2; ks++) {
#pragma unroll
            for (int cb = 0; cb < 4; cb++) {
                const int col = cb * 16 + l15;
                bf16x8 bH = *(const bf16x8*)&skh[col][ks * 32 + kk];
                bf16x8 bL = *(const bf16x8*)&skl[col][ks * 32 + kk];
                s[cb] = __builtin_amdgcn_mfma_f32_16x16x32_bf16(aH[ks], bH, s[cb], 0, 0, 0);
                s[cb] = __builtin_amdgcn_mfma_f32_16x16x32_bf16(aH[ks], bL, s[cb], 0, 0, 0);
                s[cb] = __builtin_amdgcn_mfma_f32_16x16x32_bf16(aL[ks], bH, s[cb], 0, 0, 0);
            }
        }
        float* pb = probs + (long long)c * 4194304 +
                    (long long)(row0 + wv * 16 + (lane >> 4) * 4) * 2048 + j * 64;
#pragma unroll
        for (int cb = 0; cb < 4; cb++) {
#pragma unroll
            for (int r = 0; r < 4; r++) {
                pb[(long long)r * 2048 + cb * 16 + l15] = __expf(s[cb][r] * 0.125f) * rsum[r];
            }
        }
    }
}

extern "C" void kernel_launch(void* const* d_in, const int* in_sizes, int n_in,
                              void* d_out, int out_size, void* d_ws, size_t ws_size,
                              hipStream_t stream)
{
    const float* query = (const float*)d_in[0];
    const float* key_  = (const float*)d_in[1];
    const float* value = (const float*)d_in[2];
    const float* Wq = (const float*)d_in[3];
    const float* bq = (const float*)d_in[4];
    const float* Wk = (const float*)d_in[5];
    const float* bk = (const float*)d_in[6];
    const float* Wv = (const float*)d_in[7];
    const float* bv = (const float*)d_in[8];
    const float* Wo = (const float*)d_in[9];
    const float* bo = (const float*)d_in[10];

    float* out   = (float*)d_out;
    float* probs = out + 4194304LL;

    // workspace: 6x 8MB bf16 + 4MB WT + 16MB ao = 68MB
    char* w = (char*)d_ws;
    unsigned short* qh = (unsigned short*)(w);
    unsigned short* ql = (unsigned short*)(w + (8LL << 20));
    unsigned short* kh = (unsigned short*)(w + (16LL << 20));
    unsigned short* kl = (unsigned short*)(w + (24LL << 20));
    unsigned short* vh = (unsigned short*)(w + (32LL << 20));
    unsigned short* vt = (unsigned short*)(w + (40LL << 20));
    float*          WT = (float*)(w + (48LL << 20));
    float*          ao = (float*)(w + (52LL << 20));

    transpose512<<<dim3(16, 16, 4), dim3(32, 8, 1), 0, stream>>>(Wq, Wk, Wv, Wo, WT);

    proj_qkv<<<dim3(128, 8, 3), 256, 0, stream>>>(query, key_, value, WT, bq, bk, bv,
                                                  qh, ql, kh, kl, vh);

    vtrans2<<<dim3(32, 32, 1), 256, 0, stream>>>(vh, vt);

    fused_attn<<<dim3(32, 32, 1), 256, 0, stream>>>(qh, ql, kh, kl, vt, probs, ao);

    gemm_bt<true><<<dim3(128, 8, 1), 256, 0, stream>>>(ao, 512, 0, WT + 786432, 512, 0,
                                                       out, 512, 0, bo, 1.f, 512);
}

// Round 6
// 313.238 us; speedup vs baseline: 2.1488x; 1.1419x over previous
//
#include <hip/hip_runtime.h>

// MultiheadAtt: B=4, S=2048, D=512, H=8, HD=64.  M = B*S = 8192 tokens.
// .view() reshape is a raw row-major no-op: chunk c = m>>8 (m = token index,
// 0..8191), l = (m&255)*8 + (n>>6), hd = n&63; flat [m][n] == [c][l][hd],
// 32 chunks x L=2048 x 64.
// Outputs: out (8192*512 f32) then probs (32*2048*2048 f32).
//
// Round 6 = round 5 with the REAL bug fixed: projection / out-projection
// grids must cover 8192 rows (dim3(128,8,*)), not 4096. R3-R5 failures were
// all "upper half of out never written" (absmax bit-identical 0.2636 = max
// |ref| over rows 4096..8191 vs memset zeros).

typedef __attribute__((ext_vector_type(4))) float fvec4;
typedef __attribute__((ext_vector_type(4))) float f32x4;
typedef __attribute__((ext_vector_type(8))) short bf16x8;
typedef __attribute__((ext_vector_type(4))) short bf16x4;

__device__ inline unsigned short f2bf_rne(float x) {
    unsigned u = __builtin_bit_cast(unsigned, x);
    unsigned r = (u + 0x7FFFu + ((u >> 16) & 1u)) >> 16;
    return (unsigned short)r;
}
__device__ inline float bf2f(unsigned short h) {
    unsigned u = ((unsigned)h) << 16;
    return __builtin_bit_cast(float, u);
}

// ---------------------------------------------------- prep: f32 -> bf16 hi/lo
__global__ __launch_bounds__(256) void split3(
    const float* __restrict__ X0, const float* __restrict__ X1, const float* __restrict__ X2,
    unsigned short* __restrict__ Hb, unsigned short* __restrict__ Lb)
{
    const float* X = blockIdx.z == 0 ? X0 : blockIdx.z == 1 ? X1 : X2;
    unsigned short* H = Hb + (long long)blockIdx.z * 4194304;
    unsigned short* L = Lb + (long long)blockIdx.z * 4194304;
    const long long i = (long long)(blockIdx.x * 256 + threadIdx.x) * 8;
    fvec4 a = *(const fvec4*)(X + i);
    fvec4 b = *(const fvec4*)(X + i + 4);
    bf16x8 h, l;
#pragma unroll
    for (int j = 0; j < 4; j++) {
        unsigned short hh = f2bf_rne(a[j]);
        h[j] = (short)hh; l[j] = (short)f2bf_rne(a[j] - bf2f(hh));
        hh = f2bf_rne(b[j]);
        h[4 + j] = (short)hh; l[4 + j] = (short)f2bf_rne(b[j] - bf2f(hh));
    }
    *(bf16x8*)(H + i) = h;
    *(bf16x8*)(L + i) = l;
}

// --------------------------------------- weight transpose + split to bf16 hi/lo
__global__ __launch_bounds__(256) void wtrans_split(
    const float* __restrict__ W0, const float* __restrict__ W1,
    const float* __restrict__ W2, const float* __restrict__ W3,
    unsigned short* __restrict__ TH, unsigned short* __restrict__ TL)
{
    const float* W = blockIdx.z == 0 ? W0 : blockIdx.z == 1 ? W1 : blockIdx.z == 2 ? W2 : W3;
    unsigned short* th = TH + (long long)blockIdx.z * 262144;
    unsigned short* tl = TL + (long long)blockIdx.z * 262144;
    __shared__ float t[32][33];
    const int x = threadIdx.x, y = threadIdx.y;  // block (32,8)
    const int n0 = blockIdx.x * 32, k0 = blockIdx.y * 32;
#pragma unroll
    for (int j = 0; j < 4; j++) t[y + 8 * j][x] = W[(long long)(k0 + y + 8 * j) * 512 + n0 + x];
    __syncthreads();
#pragma unroll
    for (int j = 0; j < 4; j++) {
        float v = t[x][y + 8 * j];
        unsigned short h = f2bf_rne(v);
        th[(long long)(n0 + y + 8 * j) * 512 + k0 + x] = h;
        tl[(long long)(n0 + y + 8 * j) * 512 + k0 + x] = f2bf_rne(v - bf2f(h));
    }
}

// -------------------------- split-bf16 GEMM, 64x64 tile (round-2 structure)
// C[8192][512] = A @ Bt^T + bias. A [8192][512] hi/lo bf16, Bt [512][512].
// Reg-prefetch staging; 3-term split MFMA.
template <bool SPLIT_OUT>
__global__ __launch_bounds__(256) void gemm_bs(
    const unsigned short* __restrict__ AH, const unsigned short* __restrict__ AL, long long sAz,
    const unsigned short* __restrict__ BH, const unsigned short* __restrict__ BL, long long sBz,
    const float* __restrict__ b0, const float* __restrict__ b1, const float* __restrict__ b2,
    unsigned short* __restrict__ OH, unsigned short* __restrict__ OL,
    float* __restrict__ OF, long long sOz)
{
    __shared__ __align__(16) unsigned short Ah[64][40];
    __shared__ __align__(16) unsigned short Al[64][40];
    __shared__ __align__(16) unsigned short Bh[64][40];
    __shared__ __align__(16) unsigned short Bl[64][40];

    const int tid = threadIdx.x, lane = tid & 63, wv = tid >> 6;
    const int z = blockIdx.z;
    AH += z * sAz; AL += z * sAz; BH += z * sBz; BL += z * sBz;
    const float* bias = z == 0 ? b0 : z == 1 ? b1 : b2;
    const int row0 = blockIdx.x * 64, col0 = blockIdx.y * 64;

    f32x4 acc[4];
#pragma unroll
    for (int i = 0; i < 4; i++)
#pragma unroll
        for (int r = 0; r < 4; r++) acc[i][r] = 0.f;

    const int lr = tid >> 2;          // staging row 0..63
    const int lc = (tid & 3) * 8;     // staging col chunk
    const int ar = (wv << 4) + (lane & 15);
    const int kk = (lane >> 4) << 3;

    bf16x8 ra_h, ra_l, rb_h, rb_l;
    auto ldregs = [&](int k0) {
        ra_h = *(const bf16x8*)(AH + (long long)(row0 + lr) * 512 + k0 + lc);
        ra_l = *(const bf16x8*)(AL + (long long)(row0 + lr) * 512 + k0 + lc);
        rb_h = *(const bf16x8*)(BH + (long long)(col0 + lr) * 512 + k0 + lc);
        rb_l = *(const bf16x8*)(BL + (long long)(col0 + lr) * 512 + k0 + lc);
    };

    ldregs(0);
    for (int t = 0; t < 16; t++) {
        __syncthreads();  // previous iteration's frag reads done
        *(bf16x8*)&Ah[lr][lc] = ra_h;
        *(bf16x8*)&Al[lr][lc] = ra_l;
        *(bf16x8*)&Bh[lr][lc] = rb_h;
        *(bf16x8*)&Bl[lr][lc] = rb_l;
        if (t < 15) ldregs((t + 1) * 32);
        __syncthreads();

        bf16x8 aH = *(const bf16x8*)&Ah[ar][kk];
        bf16x8 aL = *(const bf16x8*)&Al[ar][kk];
#pragma unroll
        for (int cb = 0; cb < 4; cb++) {
            const int br = (cb << 4) + (lane & 15);
            bf16x8 bH = *(const bf16x8*)&Bh[br][kk];
            bf16x8 bL = *(const bf16x8*)&Bl[br][kk];
            acc[cb] = __builtin_amdgcn_mfma_f32_16x16x32_bf16(aH, bH, acc[cb], 0, 0, 0);
            acc[cb] = __builtin_amdgcn_mfma_f32_16x16x32_bf16(aH, bL, acc[cb], 0, 0, 0);
            acc[cb] = __builtin_amdgcn_mfma_f32_16x16x32_bf16(aL, bH, acc[cb], 0, 0, 0);
        }
    }

    // C/D layout (m89-verified): col = lane&15, row = (lane>>4)*4 + reg
#pragma unroll
    for (int cb = 0; cb < 4; cb++) {
#pragma unroll
        for (int r = 0; r < 4; r++) {
            const long long row = row0 + (wv << 4) + ((lane >> 4) << 2) + r;
            const int col = col0 + (cb << 4) + (lane & 15);
            float val = acc[cb][r] + bias[col];
            if constexpr (SPLIT_OUT) {
                unsigned short h = f2bf_rne(val);
                (OH + z * sOz)[row * 512 + col] = h;
                if (z != 2)  // v needs hi only
                    (OL + z * sOz)[row * 512 + col] = f2bf_rne(val - bf2f(h));
            } else {
                (OF + z * sOz)[row * 512 + col] = val;
            }
        }
    }
}

// ----------------------------------------------- v transpose: vt[c][hd][l] bf16
__global__ __launch_bounds__(256) void vtrans2(
    const unsigned short* __restrict__ vh, unsigned short* __restrict__ vt)
{
    __shared__ __align__(16) unsigned short t[64][80];
    const int tid = threadIdx.x;
    const int c = blockIdx.y;
    const int l0 = blockIdx.x * 64;
    const long long cb = (long long)c * 131072;
    const int rrow = tid >> 3, ccol = (tid & 7) * 8;
#pragma unroll
    for (int rr = 0; rr < 2; rr++)
        *(bf16x8*)&t[rrow + rr * 32][ccol] =
            *(const bf16x8*)(vh + cb + (long long)(l0 + rrow + rr * 32) * 64 + ccol);
    __syncthreads();
#pragma unroll
    for (int rr = 0; rr < 2; rr++) {
        const int hd = rrow + rr * 32;
        bf16x8 o;
#pragma unroll
        for (int q2 = 0; q2 < 8; q2++) o[q2] = (short)t[ccol + q2][hd];
        *(bf16x8*)(vt + cb + (long long)hd * 2048 + l0 + ccol) = o;
    }
}

// --------------------------------------- fused scores + softmax + PV + probs
__global__ __launch_bounds__(256) void fused_attn(
    const unsigned short* __restrict__ qh, const unsigned short* __restrict__ ql,
    const unsigned short* __restrict__ kh, const unsigned short* __restrict__ kl,
    const unsigned short* __restrict__ vt,
    float* __restrict__ probs,
    unsigned short* __restrict__ aoh, unsigned short* __restrict__ aol)
{
    __shared__ __align__(16) unsigned short skh[64][80];
    __shared__ __align__(16) unsigned short skl[64][80];
    __shared__ __align__(16) unsigned short svt[64][80];
    __shared__ __align__(16) unsigned short sP[4][16][68];

    const int tid = threadIdx.x, lane = tid & 63, wv = tid >> 6;

    // XCD-bijective swizzle: 1024 blocks = 8 XCDs x 128; each XCD owns 4
    // consecutive chunks -> its K/V set (~3 MiB) fits the per-XCD 4 MiB L2.
    const int orig = blockIdx.y * 32 + blockIdx.x;
    const int myid = (orig & 7) * 128 + (orig >> 3);
    const int c    = myid >> 5;
    const int row0 = (myid & 31) * 64;
    const long long cbase = (long long)c * 131072;

    const int l15 = lane & 15, g = lane >> 4, kk = g * 8;
    const int srow = tid >> 3;          // staging row 0..31
    const int scol = (tid & 7) * 8;     // staging col chunk
    const int p_r0 = g * 4;

    // ---- Q fragments (held whole kernel)
    const int arow = row0 + wv * 16 + l15;
    bf16x8 aH[2], aL[2];
    {
        const unsigned short* qp  = qh + cbase + (long long)arow * 64;
        const unsigned short* qlp = ql + cbase + (long long)arow * 64;
        aH[0] = *(const bf16x8*)(qp + kk);   aH[1] = *(const bf16x8*)(qp + 32 + kk);
        aL[0] = *(const bf16x8*)(qlp + kk);  aL[1] = *(const bf16x8*)(qlp + 32 + kk);
    }

    bf16x8 rkh[2], rkl[2], rvt[2];
    auto ld1 = [&](int j) {
        const long long ktb = cbase + (long long)j * 4096;
        const long long vtb = cbase + j * 64;
#pragma unroll
        for (int rr = 0; rr < 2; rr++) {
            const int r2 = srow + rr * 32;
            rkh[rr] = *(const bf16x8*)(kh + ktb + (long long)r2 * 64 + scol);
            rkl[rr] = *(const bf16x8*)(kl + ktb + (long long)r2 * 64 + scol);
            rvt[rr] = *(const bf16x8*)(vt + vtb + (long long)r2 * 2048 + scol);
        }
    };
    auto st1 = [&]() {
#pragma unroll
        for (int rr = 0; rr < 2; rr++) {
            const int r2 = srow + rr * 32;
            *(bf16x8*)&skh[r2][scol] = rkh[rr];
            *(bf16x8*)&skl[r2][scol] = rkl[rr];
            *(bf16x8*)&svt[r2][scol] = rvt[rr];
        }
    };
    auto ld2 = [&](int j) {
        const long long ktb = cbase + (long long)j * 4096;
#pragma unroll
        for (int rr = 0; rr < 2; rr++) {
            const int r2 = srow + rr * 32;
            rkh[rr] = *(const bf16x8*)(kh + ktb + (long long)r2 * 64 + scol);
            rkl[rr] = *(const bf16x8*)(kl + ktb + (long long)r2 * 64 + scol);
        }
    };
    auto st2 = [&]() {
#pragma unroll
        for (int rr = 0; rr < 2; rr++) {
            const int r2 = srow + rr * 32;
            *(bf16x8*)&skh[r2][scol] = rkh[rr];
            *(bf16x8*)&skl[r2][scol] = rkl[rr];
        }
    };

    f32x4 acc_o[4];
#pragma unroll
    for (int i = 0; i < 4; i++)
#pragma unroll
        for (int r = 0; r < 4; r++) acc_o[i][r] = 0.f;
    float rsum[4] = {0.f, 0.f, 0.f, 0.f};

    // ---- pass 1: S, exp, row-sums, PV (unnormalized)
    ld1(0);
    for (int j = 0; j < 32; j++) {
        __syncthreads();   // prior-iter LDS reads done
        st1();
        if (j < 31) ld1(j + 1);
        __syncthreads();

        f32x4 s[4];
#pragma unroll
        for (int cb = 0; cb < 4; cb++)
#pragma unroll
            for (int r = 0; r < 4; r++) s[cb][r] = 0.f;
#pragma unroll
        for (int ks = 0; ks < 2; ks++) {
#pragma unroll
            for (int cb = 0; cb < 4; cb++) {
                const int col = cb * 16 + l15;
                bf16x8 bH = *(const bf16x8*)&skh[col][ks * 32 + kk];
                bf16x8 bL = *(const bf16x8*)&skl[col][ks * 32 + kk];
                s[cb] = __builtin_amdgcn_mfma_f32_16x16x32_bf16(aH[ks], bH, s[cb], 0, 0, 0);
                s[cb] = __builtin_amdgcn_mfma_f32_16x16x32_bf16(aH[ks], bL, s[cb], 0, 0, 0);
                s[cb] = __builtin_amdgcn_mfma_f32_16x16x32_bf16(aL[ks], bH, s[cb], 0, 0, 0);
            }
        }
#pragma unroll
        for (int cb = 0; cb < 4; cb++) {
#pragma unroll
            for (int r = 0; r < 4; r++) {
                float p = __expf(s[cb][r] * 0.125f);
                rsum[r] += p;
                sP[wv][p_r0 + r][cb * 16 + l15] = f2bf_rne(p);
            }
        }
        // PV: A-frag from own wave's sP strip (no barrier needed)
#pragma unroll
        for (int ks = 0; ks < 2; ks++) {
            bf16x4 p0 = *(const bf16x4*)&sP[wv][l15][ks * 32 + kk];
            bf16x4 p1 = *(const bf16x4*)&sP[wv][l15][ks * 32 + kk + 4];
            bf16x8 pa;
#pragma unroll
            for (int q2 = 0; q2 < 4; q2++) { pa[q2] = p0[q2]; pa[4 + q2] = p1[q2]; }
#pragma unroll
            for (int co = 0; co < 4; co++) {
                bf16x8 bV = *(const bf16x8*)&svt[co * 16 + l15][ks * 32 + kk];
                acc_o[co] = __builtin_amdgcn_mfma_f32_16x16x32_bf16(pa, bV, acc_o[co], 0, 0, 0);
            }
        }
    }

    // 1/rowsum (reduce across the 16 col-lanes)
#pragma unroll
    for (int r = 0; r < 4; r++) {
        float s = rsum[r];
        s += __shfl_xor(s, 1, 64);
        s += __shfl_xor(s, 2, 64);
        s += __shfl_xor(s, 4, 64);
        s += __shfl_xor(s, 8, 64);
        rsum[r] = 1.f / s;
    }

    // ao epilogue -> bf16 hi/lo (feeds out-projection)
#pragma unroll
    for (int co = 0; co < 4; co++) {
#pragma unroll
        for (int r = 0; r < 4; r++) {
            const long long oi = cbase + (long long)(row0 + wv * 16 + p_r0 + r) * 64 + co * 16 + l15;
            float o = acc_o[co][r] * rsum[r];
            unsigned short h = f2bf_rne(o);
            aoh[oi] = h;
            aol[oi] = f2bf_rne(o - bf2f(h));
        }
    }

    // ---- pass 2: recompute S, write normalized probs
    ld2(0);
    for (int j = 0; j < 32; j++) {
        __syncthreads();
        st2();
        if (j < 31) ld2(j + 1);
        __syncthreads();

        f32x4 s[4];
#pragma unroll
        for (int cb = 0; cb < 4; cb++)
#pragma unroll
            for (int r = 0; r < 4; r++) s[cb][r] = 0.f;
#pragma unroll
        for (int ks = 0; ks < 2; ks++) {
#pragma unroll
            for (int cb = 0; cb < 4; cb++) {
                const int col = cb * 16 + l15;
                bf16x8 bH = *(const bf16x8*)&skh[col][ks * 32 + kk];
                bf16x8 bL = *(const bf16x8*)&skl[col][ks * 32 + kk];
                s[cb] = __builtin_amdgcn_mfma_f32_16x16x32_bf16(aH[ks], bH, s[cb], 0, 0, 0);
                s[cb] = __builtin_amdgcn_mfma_f32_16x16x32_bf16(aH[ks], bL, s[cb], 0, 0, 0);
                s[cb] = __builtin_amdgcn_mfma_f32_16x16x32_bf16(aL[ks], bH, s[cb], 0, 0, 0);
            }
        }
        float* pb = probs + (long long)c * 4194304 +
                    (long long)(row0 + wv * 16 + p_r0) * 2048 + j * 64;
#pragma unroll
        for (int cb = 0; cb < 4; cb++) {
#pragma unroll
            for (int r = 0; r < 4; r++) {
                pb[(long long)r * 2048 + cb * 16 + l15] = __expf(s[cb][r] * 0.125f) * rsum[r];
            }
        }
    }
}

extern "C" void kernel_launch(void* const* d_in, const int* in_sizes, int n_in,
                              void* d_out, int out_size, void* d_ws, size_t ws_size,
                              hipStream_t stream)
{
    const float* query = (const float*)d_in[0];
    const float* key_  = (const float*)d_in[1];
    const float* value = (const float*)d_in[2];
    const float* Wq = (const float*)d_in[3];
    const float* bq = (const float*)d_in[4];
    const float* Wk = (const float*)d_in[5];
    const float* bk = (const float*)d_in[6];
    const float* Wv = (const float*)d_in[7];
    const float* bv = (const float*)d_in[8];
    const float* Wo = (const float*)d_in[9];
    const float* bo = (const float*)d_in[10];

    float* out   = (float*)d_out;
    float* probs = out + 4194304LL;

    // Transient input splits live in the probs region (512 MiB; dead before
    // fused_attn writes probs; rewritten every call). 3 x 4194304 shorts each.
    unsigned short* XH = (unsigned short*)probs;   // 24 MiB
    unsigned short* XL = XH + 3 * 4194304LL;       // 24 MiB

    // Persistent scratch in d_ws: 68 MiB total.
    const long long MiB = 1LL << 20;
    char* w = (char*)d_ws;
    unsigned short* QKVH = (unsigned short*)(w + 0 * MiB);   // 24 MiB (qh,kh,vh)
    unsigned short* QKVL = (unsigned short*)(w + 24 * MiB);  // 16 MiB (ql,kl)
    unsigned short* WTH  = (unsigned short*)(w + 40 * MiB);  // 2 MiB
    unsigned short* WTL  = (unsigned short*)(w + 42 * MiB);  // 2 MiB
    unsigned short* VT   = (unsigned short*)(w + 44 * MiB);  // 8 MiB
    unsigned short* AOH  = (unsigned short*)(w + 52 * MiB);  // 8 MiB
    unsigned short* AOL  = (unsigned short*)(w + 60 * MiB);  // 8 MiB

    split3<<<dim3(2048, 1, 3), 256, 0, stream>>>(query, key_, value, XH, XL);
    wtrans_split<<<dim3(16, 16, 4), dim3(32, 8, 1), 0, stream>>>(Wq, Wk, Wv, Wo, WTH, WTL);

    // q/k/v projections (z = 0,1,2); M = 8192 rows -> grid.x = 128
    gemm_bs<true><<<dim3(128, 8, 3), 256, 0, stream>>>(
        XH, XL, 4194304, WTH, WTL, 262144, bq, bk, bv,
        QKVH, QKVL, nullptr, 4194304);

    vtrans2<<<dim3(32, 32, 1), 256, 0, stream>>>(QKVH + 2 * 4194304LL, VT);

    fused_attn<<<dim3(32, 32, 1), 256, 0, stream>>>(
        QKVH, QKVL, QKVH + 4194304LL, QKVL + 4194304LL, VT, probs, AOH, AOL);

    // out = ao @ Wo + bo; M = 8192 rows -> grid.x = 128
    gemm_bs<false><<<dim3(128, 8, 1), 256, 0, stream>>>(
        AOH, AOL, 0, WTH + 3 * 262144LL, WTL + 3 * 262144LL, 0, bo, bo, bo,
        nullptr, nullptr, out, 0);
}

// Round 7
// 297.903 us; speedup vs baseline: 2.2594x; 1.0515x over previous
//
#include <hip/hip_runtime.h>

// MultiheadAtt: B=4, S=2048, D=512, H=8, HD=64.  M = B*S = 8192 tokens.
// .view() reshape is a raw row-major no-op: chunk c = m>>8, l = (m&255)*8 +
// (n>>6), hd = n&63; flat [m][n] == [c][l][hd] (32 chunks x 2048 x 64).
// Outputs: out (8192*512 f32) then probs (32*2048*2048 f32).
//
// Round 7 = round 6 + 128^2-tile global_load_lds double-buffered GEMM for the
// projections and out-projection (the R3/R4 gemm_split — exonerated; its only
// bug was the M=4096 grid). fused_attn unchanged from the passing R6 version.

typedef __attribute__((ext_vector_type(4))) float fvec4;
typedef __attribute__((ext_vector_type(4))) float f32x4;
typedef __attribute__((ext_vector_type(8))) short bf16x8;
typedef __attribute__((ext_vector_type(4))) short bf16x4;

typedef const __attribute__((address_space(1))) unsigned int* gas_t;
typedef __attribute__((address_space(3))) unsigned int* las_t;

__device__ inline void gl_lds16(const void* g, void* l) {
    __builtin_amdgcn_global_load_lds((gas_t)g, (las_t)l, 16, 0, 0);
}

__device__ inline unsigned short f2bf_rne(float x) {
    unsigned u = __builtin_bit_cast(unsigned, x);
    unsigned r = (u + 0x7FFFu + ((u >> 16) & 1u)) >> 16;
    return (unsigned short)r;
}
__device__ inline float bf2f(unsigned short h) {
    unsigned u = ((unsigned)h) << 16;
    return __builtin_bit_cast(float, u);
}

// swizzled LDS frag offset (shorts), 32-short rows: 4 chunks, XOR (row>>1)&3
__device__ inline int fo4(int row, int ch) { return row * 32 + ((ch ^ ((row >> 1) & 3)) * 8); }

// ---------------------------------------------------- prep: f32 -> bf16 hi/lo
__global__ __launch_bounds__(256) void split3(
    const float* __restrict__ X0, const float* __restrict__ X1, const float* __restrict__ X2,
    unsigned short* __restrict__ Hb, unsigned short* __restrict__ Lb)
{
    const float* X = blockIdx.z == 0 ? X0 : blockIdx.z == 1 ? X1 : X2;
    unsigned short* H = Hb + (long long)blockIdx.z * 4194304;
    unsigned short* L = Lb + (long long)blockIdx.z * 4194304;
    const long long i = (long long)(blockIdx.x * 256 + threadIdx.x) * 8;
    fvec4 a = *(const fvec4*)(X + i);
    fvec4 b = *(const fvec4*)(X + i + 4);
    bf16x8 h, l;
#pragma unroll
    for (int j = 0; j < 4; j++) {
        unsigned short hh = f2bf_rne(a[j]);
        h[j] = (short)hh; l[j] = (short)f2bf_rne(a[j] - bf2f(hh));
        hh = f2bf_rne(b[j]);
        h[4 + j] = (short)hh; l[4 + j] = (short)f2bf_rne(b[j] - bf2f(hh));
    }
    *(bf16x8*)(H + i) = h;
    *(bf16x8*)(L + i) = l;
}

// --------------------------------------- weight transpose + split to bf16 hi/lo
__global__ __launch_bounds__(256) void wtrans_split(
    const float* __restrict__ W0, const float* __restrict__ W1,
    const float* __restrict__ W2, const float* __restrict__ W3,
    unsigned short* __restrict__ TH, unsigned short* __restrict__ TL)
{
    const float* W = blockIdx.z == 0 ? W0 : blockIdx.z == 1 ? W1 : blockIdx.z == 2 ? W2 : W3;
    unsigned short* th = TH + (long long)blockIdx.z * 262144;
    unsigned short* tl = TL + (long long)blockIdx.z * 262144;
    __shared__ float t[32][33];
    const int x = threadIdx.x, y = threadIdx.y;  // block (32,8)
    const int n0 = blockIdx.x * 32, k0 = blockIdx.y * 32;
#pragma unroll
    for (int j = 0; j < 4; j++) t[y + 8 * j][x] = W[(long long)(k0 + y + 8 * j) * 512 + n0 + x];
    __syncthreads();
#pragma unroll
    for (int j = 0; j < 4; j++) {
        float v = t[x][y + 8 * j];
        unsigned short h = f2bf_rne(v);
        th[(long long)(n0 + y + 8 * j) * 512 + k0 + x] = h;
        tl[(long long)(n0 + y + 8 * j) * 512 + k0 + x] = f2bf_rne(v - bf2f(h));
    }
}

// ------------------------------------------------- split-bf16 GEMM, 128x128 tile
// C[8192][512] = A @ Bt^T + bias. 3-term split MFMA; dbuf global_load_lds.
// Grid: (M/128, N/128, nz). Wave w stages one of {Ah,Al,Bh,Bl}.
template <bool SPLIT_OUT>
__global__ __launch_bounds__(256) void gemm_split(
    const unsigned short* __restrict__ AH, const unsigned short* __restrict__ AL, long long sAz,
    const unsigned short* __restrict__ BH, const unsigned short* __restrict__ BL, long long sBz,
    const float* __restrict__ b0, const float* __restrict__ b1, const float* __restrict__ b2,
    unsigned short* __restrict__ OH, unsigned short* __restrict__ OL,
    float* __restrict__ OF, long long sOz)
{
    __shared__ __align__(16) unsigned short sAh[2][4096];
    __shared__ __align__(16) unsigned short sAl[2][4096];
    __shared__ __align__(16) unsigned short sBh[2][4096];
    __shared__ __align__(16) unsigned short sBl[2][4096];

    const int tid = threadIdx.x, lane = tid & 63, wv = tid >> 6;
    const int z = blockIdx.z;
    AH += z * sAz; AL += z * sAz; BH += z * sBz; BL += z * sBz;
    const float* bias = z == 0 ? b0 : z == 1 ? b1 : b2;
    const int row0 = blockIdx.x * 128, col0 = blockIdx.y * 128;
    const int wr = wv >> 1, wc = wv & 1;
    const int l15 = lane & 15, g = lane >> 4;

    // staging: wave -> one array, whole 128x32 tile (8 insts of 1KB)
    const unsigned short* src = wv == 0 ? AH + (long long)row0 * 512
                              : wv == 1 ? AL + (long long)row0 * 512
                              : wv == 2 ? BH + (long long)col0 * 512
                              :           BL + (long long)col0 * 512;
    unsigned short* dst = wv == 0 ? &sAh[0][0] : wv == 1 ? &sAl[0][0]
                        : wv == 2 ? &sBh[0][0] : &sBl[0][0];
    const int srow = lane >> 2;                       // row within 16-row group
    const int csrc = (lane & 3) ^ ((lane >> 3) & 3);  // inverse of fo4 swizzle

    f32x4 acc[4][4];
#pragma unroll
    for (int a = 0; a < 4; a++)
#pragma unroll
        for (int b = 0; b < 4; b++)
#pragma unroll
            for (int r = 0; r < 4; r++) acc[a][b][r] = 0.f;

    auto stage = [&](int buf, int k0) {
#pragma unroll
        for (int i = 0; i < 8; i++) {
            gl_lds16(src + (long long)(i * 16 + srow) * 512 + k0 + csrc * 8,
                     dst + buf * 4096 + i * 512);
        }
    };

    stage(0, 0);
    __syncthreads();
    int cur = 0;
    for (int t = 0; t < 16; t++) {
        if (t < 15) stage(cur ^ 1, (t + 1) * 32);
        bf16x8 aHf[4], aLf[4];
#pragma unroll
        for (int rb = 0; rb < 4; rb++) {
            const int r = wr * 64 + rb * 16 + l15;
            aHf[rb] = *(const bf16x8*)&sAh[cur][fo4(r, g)];
            aLf[rb] = *(const bf16x8*)&sAl[cur][fo4(r, g)];
        }
#pragma unroll
        for (int cb = 0; cb < 4; cb++) {
            const int rB = wc * 64 + cb * 16 + l15;
            bf16x8 bH = *(const bf16x8*)&sBh[cur][fo4(rB, g)];
            bf16x8 bL = *(const bf16x8*)&sBl[cur][fo4(rB, g)];
#pragma unroll
            for (int rb = 0; rb < 4; rb++) {
                acc[rb][cb] = __builtin_amdgcn_mfma_f32_16x16x32_bf16(aHf[rb], bH, acc[rb][cb], 0, 0, 0);
                acc[rb][cb] = __builtin_amdgcn_mfma_f32_16x16x32_bf16(aHf[rb], bL, acc[rb][cb], 0, 0, 0);
                acc[rb][cb] = __builtin_amdgcn_mfma_f32_16x16x32_bf16(aLf[rb], bH, acc[rb][cb], 0, 0, 0);
            }
        }
        __syncthreads();
        cur ^= 1;
    }

#pragma unroll
    for (int rb = 0; rb < 4; rb++) {
#pragma unroll
        for (int cb = 0; cb < 4; cb++) {
            const int col = col0 + wc * 64 + cb * 16 + l15;
#pragma unroll
            for (int rr = 0; rr < 4; rr++) {
                const long long row = row0 + wr * 64 + rb * 16 + g * 4 + rr;
                float val = acc[rb][cb][rr] + bias[col];
                if constexpr (SPLIT_OUT) {
                    unsigned short h = f2bf_rne(val);
                    (OH + z * sOz)[row * 512 + col] = h;
                    if (z != 2)  // v needs hi only
                        (OL + z * sOz)[row * 512 + col] = f2bf_rne(val - bf2f(h));
                } else {
                    (OF + z * sOz)[row * 512 + col] = val;
                }
            }
        }
    }
}

// ----------------------------------------------- v transpose: vt[c][hd][l] bf16
__global__ __launch_bounds__(256) void vtrans2(
    const unsigned short* __restrict__ vh, unsigned short* __restrict__ vt)
{
    __shared__ __align__(16) unsigned short t[64][80];
    const int tid = threadIdx.x;
    const int c = blockIdx.y;
    const int l0 = blockIdx.x * 64;
    const long long cb = (long long)c * 131072;
    const int rrow = tid >> 3, ccol = (tid & 7) * 8;
#pragma unroll
    for (int rr = 0; rr < 2; rr++)
        *(bf16x8*)&t[rrow + rr * 32][ccol] =
            *(const bf16x8*)(vh + cb + (long long)(l0 + rrow + rr * 32) * 64 + ccol);
    __syncthreads();
#pragma unroll
    for (int rr = 0; rr < 2; rr++) {
        const int hd = rrow + rr * 32;
        bf16x8 o;
#pragma unroll
        for (int q2 = 0; q2 < 8; q2++) o[q2] = (short)t[ccol + q2][hd];
        *(bf16x8*)(vt + cb + (long long)hd * 2048 + l0 + ccol) = o;
    }
}

// --------------------------------------- fused scores + softmax + PV + probs
__global__ __launch_bounds__(256) void fused_attn(
    const unsigned short* __restrict__ qh, const unsigned short* __restrict__ ql,
    const unsigned short* __restrict__ kh, const unsigned short* __restrict__ kl,
    const unsigned short* __restrict__ vt,
    float* __restrict__ probs,
    unsigned short* __restrict__ aoh, unsigned short* __restrict__ aol)
{
    __shared__ __align__(16) unsigned short skh[64][80];
    __shared__ __align__(16) unsigned short skl[64][80];
    __shared__ __align__(16) unsigned short svt[64][80];
    __shared__ __align__(16) unsigned short sP[4][16][68];

    const int tid = threadIdx.x, lane = tid & 63, wv = tid >> 6;

    // XCD-bijective swizzle: 1024 blocks = 8 XCDs x 128; each XCD owns 4
    // consecutive chunks -> its K/V set (~3 MiB) fits the per-XCD 4 MiB L2.
    const int orig = blockIdx.y * 32 + blockIdx.x;
    const int myid = (orig & 7) * 128 + (orig >> 3);
    const int c    = myid >> 5;
    const int row0 = (myid & 31) * 64;
    const long long cbase = (long long)c * 131072;

    const int l15 = lane & 15, g = lane >> 4, kk = g * 8;
    const int srow = tid >> 3;          // staging row 0..31
    const int scol = (tid & 7) * 8;     // staging col chunk
    const int p_r0 = g * 4;

    // ---- Q fragments (held whole kernel)
    const int arow = row0 + wv * 16 + l15;
    bf16x8 aH[2], aL[2];
    {
        const unsigned short* qp  = qh + cbase + (long long)arow * 64;
        const unsigned short* qlp = ql + cbase + (long long)arow * 64;
        aH[0] = *(const bf16x8*)(qp + kk);   aH[1] = *(const bf16x8*)(qp + 32 + kk);
        aL[0] = *(const bf16x8*)(qlp + kk);  aL[1] = *(const bf16x8*)(qlp + 32 + kk);
    }

    bf16x8 rkh[2], rkl[2], rvt[2];
    auto ld1 = [&](int j) {
        const long long ktb = cbase + (long long)j * 4096;
        const long long vtb = cbase + j * 64;
#pragma unroll
        for (int rr = 0; rr < 2; rr++) {
            const int r2 = srow + rr * 32;
            rkh[rr] = *(const bf16x8*)(kh + ktb + (long long)r2 * 64 + scol);
            rkl[rr] = *(const bf16x8*)(kl + ktb + (long long)r2 * 64 + scol);
            rvt[rr] = *(const bf16x8*)(vt + vtb + (long long)r2 * 2048 + scol);
        }
    };
    auto st1 = [&]() {
#pragma unroll
        for (int rr = 0; rr < 2; rr++) {
            const int r2 = srow + rr * 32;
            *(bf16x8*)&skh[r2][scol] = rkh[rr];
            *(bf16x8*)&skl[r2][scol] = rkl[rr];
            *(bf16x8*)&svt[r2][scol] = rvt[rr];
        }
    };
    auto ld2 = [&](int j) {
        const long long ktb = cbase + (long long)j * 4096;
#pragma unroll
        for (int rr = 0; rr < 2; rr++) {
            const int r2 = srow + rr * 32;
            rkh[rr] = *(const bf16x8*)(kh + ktb + (long long)r2 * 64 + scol);
            rkl[rr] = *(const bf16x8*)(kl + ktb + (long long)r2 * 64 + scol);
        }
    };
    auto st2 = [&]() {
#pragma unroll
        for (int rr = 0; rr < 2; rr++) {
            const int r2 = srow + rr * 32;
            *(bf16x8*)&skh[r2][scol] = rkh[rr];
            *(bf16x8*)&skl[r2][scol] = rkl[rr];
        }
    };

    f32x4 acc_o[4];
#pragma unroll
    for (int i = 0; i < 4; i++)
#pragma unroll
        for (int r = 0; r < 4; r++) acc_o[i][r] = 0.f;
    float rsum[4] = {0.f, 0.f, 0.f, 0.f};

    // ---- pass 1: S, exp, row-sums, PV (unnormalized)
    ld1(0);
    for (int j = 0; j < 32; j++) {
        __syncthreads();   // prior-iter LDS reads done
        st1();
        if (j < 31) ld1(j + 1);
        __syncthreads();

        f32x4 s[4];
#pragma unroll
        for (int cb = 0; cb < 4; cb++)
#pragma unroll
            for (int r = 0; r < 4; r++) s[cb][r] = 0.f;
#pragma unroll
        for (int ks = 0; ks < 2; ks++) {
#pragma unroll
            for (int cb = 0; cb < 4; cb++) {
                const int col = cb * 16 + l15;
                bf16x8 bH = *(const bf16x8*)&skh[col][ks * 32 + kk];
                bf16x8 bL = *(const bf16x8*)&skl[col][ks * 32 + kk];
                s[cb] = __builtin_amdgcn_mfma_f32_16x16x32_bf16(aH[ks], bH, s[cb], 0, 0, 0);
                s[cb] = __builtin_amdgcn_mfma_f32_16x16x32_bf16(aH[ks], bL, s[cb], 0, 0, 0);
                s[cb] = __builtin_amdgcn_mfma_f32_16x16x32_bf16(aL[ks], bH, s[cb], 0, 0, 0);
            }
        }
#pragma unroll
        for (int cb = 0; cb < 4; cb++) {
#pragma unroll
            for (int r = 0; r < 4; r++) {
                float p = __expf(s[cb][r] * 0.125f);
                rsum[r] += p;
                sP[wv][p_r0 + r][cb * 16 + l15] = f2bf_rne(p);
            }
        }
        // PV: A-frag from own wave's sP strip (no barrier needed)
#pragma unroll
        for (int ks = 0; ks < 2; ks++) {
            bf16x4 p0 = *(const bf16x4*)&sP[wv][l15][ks * 32 + kk];
            bf16x4 p1 = *(const bf16x4*)&sP[wv][l15][ks * 32 + kk + 4];
            bf16x8 pa;
#pragma unroll
            for (int q2 = 0; q2 < 4; q2++) { pa[q2] = p0[q2]; pa[4 + q2] = p1[q2]; }
#pragma unroll
            for (int co = 0; co < 4; co++) {
                bf16x8 bV = *(const bf16x8*)&svt[co * 16 + l15][ks * 32 + kk];
                acc_o[co] = __builtin_amdgcn_mfma_f32_16x16x32_bf16(pa, bV, acc_o[co], 0, 0, 0);
            }
        }
    }

    // 1/rowsum (reduce across the 16 col-lanes)
#pragma unroll
    for (int r = 0; r < 4; r++) {
        float s = rsum[r];
        s += __shfl_xor(s, 1, 64);
        s += __shfl_xor(s, 2, 64);
        s += __shfl_xor(s, 4, 64);
        s += __shfl_xor(s, 8, 64);
        rsum[r] = 1.f / s;
    }

    // ao epilogue -> bf16 hi/lo (feeds out-projection)
#pragma unroll
    for (int co = 0; co < 4; co++) {
#pragma unroll
        for (int r = 0; r < 4; r++) {
            const long long oi = cbase + (long long)(row0 + wv * 16 + p_r0 + r) * 64 + co * 16 + l15;
            float o = acc_o[co][r] * rsum[r];
            unsigned short h = f2bf_rne(o);
            aoh[oi] = h;
            aol[oi] = f2bf_rne(o - bf2f(h));
        }
    }

    // ---- pass 2: recompute S, write normalized probs
    ld2(0);
    for (int j = 0; j < 32; j++) {
        __syncthreads();
        st2();
        if (j < 31) ld2(j + 1);
        __syncthreads();

        f32x4 s[4];
#pragma unroll
        for (int cb = 0; cb < 4; cb++)
#pragma unroll
            for (int r = 0; r < 4; r++) s[cb][r] = 0.f;
#pragma unroll
        for (int ks = 0; ks < 2; ks++) {
#pragma unroll
            for (int cb = 0; cb < 4; cb++) {
                const int col = cb * 16 + l15;
                bf16x8 bH = *(const bf16x8*)&skh[col][ks * 32 + kk];
                bf16x8 bL = *(const bf16x8*)&skl[col][ks * 32 + kk];
                s[cb] = __builtin_amdgcn_mfma_f32_16x16x32_bf16(aH[ks], bH, s[cb], 0, 0, 0);
                s[cb] = __builtin_amdgcn_mfma_f32_16x16x32_bf16(aH[ks], bL, s[cb], 0, 0, 0);
                s[cb] = __builtin_amdgcn_mfma_f32_16x16x32_bf16(aL[ks], bH, s[cb], 0, 0, 0);
            }
        }
        float* pb = probs + (long long)c * 4194304 +
                    (long long)(row0 + wv * 16 + p_r0) * 2048 + j * 64;
#pragma unroll
        for (int cb = 0; cb < 4; cb++) {
#pragma unroll
            for (int r = 0; r < 4; r++) {
                pb[(long long)r * 2048 + cb * 16 + l15] = __expf(s[cb][r] * 0.125f) * rsum[r];
            }
        }
    }
}

extern "C" void kernel_launch(void* const* d_in, const int* in_sizes, int n_in,
                              void* d_out, int out_size, void* d_ws, size_t ws_size,
                              hipStream_t stream)
{
    const float* query = (const float*)d_in[0];
    const float* key_  = (const float*)d_in[1];
    const float* value = (const float*)d_in[2];
    const float* Wq = (const float*)d_in[3];
    const float* bq = (const float*)d_in[4];
    const float* Wk = (const float*)d_in[5];
    const float* bk = (const float*)d_in[6];
    const float* Wv = (const float*)d_in[7];
    const float* bv = (const float*)d_in[8];
    const float* Wo = (const float*)d_in[9];
    const float* bo = (const float*)d_in[10];

    float* out   = (float*)d_out;
    float* probs = out + 4194304LL;

    // Transient input splits live in the probs region (512 MiB; dead before
    // fused_attn writes probs; rewritten every call). 3 x 4194304 shorts each.
    unsigned short* XH = (unsigned short*)probs;   // 24 MiB
    unsigned short* XL = XH + 3 * 4194304LL;       // 24 MiB

    // Persistent scratch in d_ws: 68 MiB total.
    const long long MiB = 1LL << 20;
    char* w = (char*)d_ws;
    unsigned short* QKVH = (unsigned short*)(w + 0 * MiB);   // 24 MiB (qh,kh,vh)
    unsigned short* QKVL = (unsigned short*)(w + 24 * MiB);  // 16 MiB (ql,kl)
    unsigned short* WTH  = (unsigned short*)(w + 40 * MiB);  // 2 MiB
    unsigned short* WTL  = (unsigned short*)(w + 42 * MiB);  // 2 MiB
    unsigned short* VT   = (unsigned short*)(w + 44 * MiB);  // 8 MiB
    unsigned short* AOH  = (unsigned short*)(w + 52 * MiB);  // 8 MiB
    unsigned short* AOL  = (unsigned short*)(w + 60 * MiB);  // 8 MiB

    split3<<<dim3(2048, 1, 3), 256, 0, stream>>>(query, key_, value, XH, XL);
    wtrans_split<<<dim3(16, 16, 4), dim3(32, 8, 1), 0, stream>>>(Wq, Wk, Wv, Wo, WTH, WTL);

    // q/k/v projections (z = 0,1,2); M = 8192 rows, N = 512 -> grid (64,4,3)
    gemm_split<true><<<dim3(64, 4, 3), 256, 0, stream>>>(
        XH, XL, 4194304, WTH, WTL, 262144, bq, bk, bv,
        QKVH, QKVL, nullptr, 4194304);

    vtrans2<<<dim3(32, 32, 1), 256, 0, stream>>>(QKVH + 2 * 4194304LL, VT);

    fused_attn<<<dim3(32, 32, 1), 256, 0, stream>>>(
        QKVH, QKVL, QKVH + 4194304LL, QKVL + 4194304LL, VT, probs, AOH, AOL);

    // out = ao @ Wo + bo; grid (64,4,1)
    gemm_split<false><<<dim3(64, 4, 1), 256, 0, stream>>>(
        AOH, AOL, 0, WTH + 3 * 262144LL, WTL + 3 * 262144LL, 0, bo, bo, bo,
        nullptr, nullptr, out, 0);
}